// Round 13
// baseline (1011.518 us; speedup 1.0000x reference)
//
#include <hip/hip_runtime.h>
#include <hip/hip_bf16.h>

// Bidirectional GRU (T=512,B=512,E=128,H=64) + word attention, f32.
// Pipeline: xgv (vocab-folded input projection) -> gru_scan (r12: 3-wave
// gate-split, 64 resident weights/lane, LDS h-broadcast) -> attn scores
// (scalar-pipe GEMM, r11) -> fused softmax-over-T + weighted sum.
//
// [r13 = r12 resubmitted unchanged (r12 hit an acquisition timeout).
//  Pending A/B vs r11 bench: gru_scan 355us @ VGPR=132 (remat, 1 wave/SIMD)
//  -> 3-wave gate-split, 64 weights/lane (under the ~130-VGPR allocator
//  ceiling proven in r8-r11), LDS h-broadcast, 2 barriers/step, 3/SIMD.
//  Predict: scan -> ~180-230us, total 797 -> ~620-670us.
//  History: r1=1525; r5=1240 (scan unroll); r11=797 (attn scalar-pipe GEMM
//  WIN -- lesson: stay under the allocator ceiling, don't fight it).]

#define T_LEN 512
#define B_SZ  512
#define E_DIM 128
#define H_DIM 64
#define G3    192          // 3*H
#define V_SZ  50001
#define TWOH  128

// workspace offsets (in floats)
#define XGV_SZ (V_SZ * G3)                 // 9,600,192
#define HS_SZ  (T_LEN * B_SZ * H_DIM)      // 16,777,216
#define OFF_XGV_F 0
#define OFF_XGV_B (XGV_SZ)
#define OFF_HS_F  (2 * XGV_SZ)
#define OFF_HS_B  (2 * XGV_SZ + HS_SZ)
#define OFF_SC    (2 * XGV_SZ + 2 * HS_SZ) // scores [B][T]
// total ws: 53,016,960 floats = 212 MB

__device__ __forceinline__ float sigm(float x) {
    return 1.0f / (1.0f + __expf(-x));
}
__device__ __forceinline__ float tanh_fast(float x) {
    float ax = fminf(fabsf(x), 15.0f);
    float e  = __expf(2.0f * ax);
    float r  = 1.0f - 2.0f / (e + 1.0f);
    return copysignf(r, x);
}

// ---------------------------------------------------------------------------
// Kernel A: xgv[v][g] = b_ih[g] + sum_e embed[v][e] * w_ih[g][e]  (per dir)
// block 256 = 4 waves; block covers 64 vocab rows; lane j owns gate columns
// {j, 64+j, 128+j}; wave s covers rows s+4k.
// ---------------------------------------------------------------------------
__global__ __launch_bounds__(256, 2) void xgv_kernel(
    const float* __restrict__ embed,
    const float* __restrict__ w_ih_f, const float* __restrict__ b_ih_f,
    const float* __restrict__ w_ih_b, const float* __restrict__ b_ih_b,
    float* __restrict__ ws)
{
    const int dir = blockIdx.y;
    const float* __restrict__ w_ih = dir ? w_ih_b : w_ih_f;
    const float* __restrict__ b_ih = dir ? b_ih_b : b_ih_f;
    float* __restrict__ xgv = ws + (dir ? OFF_XGV_B : OFF_XGV_F);
    const int v0 = blockIdx.x * 64;
    const int j  = threadIdx.x & 63;
    const int s  = threadIdx.x >> 6;

    float accr[16], accz[16], accn[16];
#pragma unroll
    for (int k = 0; k < 16; ++k) { accr[k] = 0.f; accz[k] = 0.f; accn[k] = 0.f; }

#pragma unroll 1
    for (int ec = 0; ec < 4; ++ec) {
        float wrc[32], wzc[32], wnc[32];
        const float4* wpr = (const float4*)(w_ih + (j      ) * 128 + ec * 32);
        const float4* wpz = (const float4*)(w_ih + (64  + j) * 128 + ec * 32);
        const float4* wpn = (const float4*)(w_ih + (128 + j) * 128 + ec * 32);
#pragma unroll
        for (int i = 0; i < 8; ++i) {
            float4 a = wpr[i];
            wrc[4*i+0] = a.x; wrc[4*i+1] = a.y; wrc[4*i+2] = a.z; wrc[4*i+3] = a.w;
            float4 b = wpz[i];
            wzc[4*i+0] = b.x; wzc[4*i+1] = b.y; wzc[4*i+2] = b.z; wzc[4*i+3] = b.w;
            float4 c = wpn[i];
            wnc[4*i+0] = c.x; wnc[4*i+1] = c.y; wnc[4*i+2] = c.z; wnc[4*i+3] = c.w;
        }
#pragma unroll
        for (int k = 0; k < 16; ++k) {
            const int v = v0 + s + 4 * k;
            if (v < V_SZ) {
                const float4* ep = (const float4*)(embed + v * 128 + ec * 32);
#pragma unroll
                for (int i = 0; i < 8; ++i) {
                    float4 e4 = ep[i];
                    accr[k] = fmaf(e4.x, wrc[4*i+0], accr[k]);
                    accr[k] = fmaf(e4.y, wrc[4*i+1], accr[k]);
                    accr[k] = fmaf(e4.z, wrc[4*i+2], accr[k]);
                    accr[k] = fmaf(e4.w, wrc[4*i+3], accr[k]);
                    accz[k] = fmaf(e4.x, wzc[4*i+0], accz[k]);
                    accz[k] = fmaf(e4.y, wzc[4*i+1], accz[k]);
                    accz[k] = fmaf(e4.z, wzc[4*i+2], accz[k]);
                    accz[k] = fmaf(e4.w, wzc[4*i+3], accz[k]);
                    accn[k] = fmaf(e4.x, wnc[4*i+0], accn[k]);
                    accn[k] = fmaf(e4.y, wnc[4*i+1], accn[k]);
                    accn[k] = fmaf(e4.z, wnc[4*i+2], accn[k]);
                    accn[k] = fmaf(e4.w, wnc[4*i+3], accn[k]);
                }
            }
        }
    }
    const float br = b_ih[j], bz = b_ih[64 + j], bn = b_ih[128 + j];
#pragma unroll
    for (int k = 0; k < 16; ++k) {
        const int v = v0 + s + 4 * k;
        if (v < V_SZ) {
            float* o = xgv + (size_t)v * G3;
            o[j]        = accr[k] + br;
            o[64 + j]   = accz[k] + bz;
            o[128 + j]  = accn[k] + bn;
        }
    }
}

// ---------------------------------------------------------------------------
// Kernel B (r12 rewrite): 3-wave gate-split GRU scan.
// Block 192 thr = 3 waves = one (b,dir) row; wave g owns gate g (r/z/n);
// lane j owns column j with w_hh[g*64+j][0..63] in 64 resident VGPRs
// (UNDER the allocator's ~130 ceiling -- the r11 lesson). h_{t} lives in
// LDS; dot product streams it via 16 broadcast ds_read_b128 (all lanes same
// addr = free). Exchange r/z/hn through LDS, 2 barriers/step; every wave
// redundantly computes the h-update (avoids a 3rd sync). 3072 waves total
// = 3 waves/SIMD (vs 1 before) hides xgv-gather + LDS latency.
// ---------------------------------------------------------------------------
__global__ __launch_bounds__(192, 2)
void gru_scan_kernel(
    const int*   __restrict__ input,
    const float* __restrict__ h0,
    const float* __restrict__ w_hh_f, const float* __restrict__ b_hh_f,
    const float* __restrict__ w_hh_b, const float* __restrict__ b_hh_b,
    float* __restrict__ ws, float* __restrict__ d_out)
{
    const int dir = blockIdx.y;
    const int tid = threadIdx.x;
    const int j   = tid & 63;
    const int g   = tid >> 6;       // gate: 0=r, 1=z, 2=n
    const int b   = blockIdx.x;

    const float* __restrict__ w_hh = dir ? w_hh_b : w_hh_f;
    const float* __restrict__ b_hh = dir ? b_hh_b : b_hh_f;
    const float* __restrict__ xgv  = ws + (dir ? OFF_XGV_B : OFF_XGV_F);
    float* __restrict__ hs = ws + (dir ? OFF_HS_B : OFF_HS_F);

    __shared__ float h_l[64];
    __shared__ float r_l[64];
    __shared__ float z_l[64];
    __shared__ float hn_l[64];

    // 64 resident weights: w[h] = w_hh[g*64+j][h]
    float w[64];
    {
        const float4* p = (const float4*)(w_hh + (g * 64 + j) * 64);
#pragma unroll
        for (int i = 0; i < 16; ++i) {
            float4 a = p[i];
            w[4*i+0] = a.x; w[4*i+1] = a.y; w[4*i+2] = a.z; w[4*i+3] = a.w;
        }
    }
    const float bg = b_hh[g * 64 + j];

    float hprev = h0[dir * (B_SZ * H_DIM) + b * H_DIM + j];
    if (g == 0) h_l[j] = hprev;

    // x pipeline: xg = this wave's gate column, xn needed by all for update.
    int tok0 = __builtin_amdgcn_readfirstlane(input[(dir ? (T_LEN - 1) : 0) * B_SZ + b]);
    int tok_next_raw = input[(dir ? (T_LEN - 2) : 1) * B_SZ + b];
    float xg = xgv[(size_t)tok0 * G3 + g * 64 + j];
    float xn = (g == 2) ? xg : xgv[(size_t)tok0 * G3 + 128 + j];

    __syncthreads();

    for (int t = 0; t < T_LEN; ++t) {
        // token prefetch t+2
        int tok_pf_raw = 0;
        if (t + 2 < T_LEN) {
            const int te2 = dir ? (T_LEN - 3 - t) : (t + 2);
            tok_pf_raw = input[te2 * B_SZ + b];
        }
        // x prefetch t+1
        float nxg = 0.f, nxn = 0.f;
        if (t + 1 < T_LEN) {
            const int tn = __builtin_amdgcn_readfirstlane(tok_next_raw);
            nxg = xgv[(size_t)tn * G3 + g * 64 + j];
            nxn = (g == 2) ? nxg : xgv[(size_t)tn * G3 + 128 + j];
        }

        // phase 1: gate pre-activation, h streamed from LDS (broadcast).
        float a0 = bg, a1 = 0.f;
#pragma unroll
        for (int i = 0; i < 16; ++i) {
            const float4 hv = *(const float4*)(h_l + 4 * i);
            a0 = fmaf(hv.x, w[4*i+0], a0);
            a1 = fmaf(hv.y, w[4*i+1], a1);
            a0 = fmaf(hv.z, w[4*i+2], a0);
            a1 = fmaf(hv.w, w[4*i+3], a1);
        }
        const float acc = a0 + a1;

        if (g == 0)      r_l[j]  = sigm(xg + acc);
        else if (g == 1) z_l[j]  = sigm(xg + acc);
        else             hn_l[j] = acc;
        __syncthreads();

        // phase 2: all waves redundantly compute the update (no 3rd sync).
        const float rr = r_l[j], zz = z_l[j], hh = hn_l[j];
        const float n    = tanh_fast(xn + rr * hh);
        const float hnew = (1.0f - zz) * n + zz * hprev;
        hprev = hnew;

        if (g == 0) {
            h_l[j] = hnew;
            const int te = dir ? (T_LEN - 1 - t) : t;   // time-aligned store
            hs[(size_t)te * (B_SZ * H_DIM) + b * H_DIM + j] = hnew;
        }
        __syncthreads();

        xg = nxg; xn = nxn;
        tok_next_raw = tok_pf_raw;
    }
    if (g == 0)
        d_out[B_SZ * TWOH + dir * (B_SZ * H_DIM) + b * H_DIM + j] = hprev;
}

// ---------------------------------------------------------------------------
// Kernel C (r11, unchanged): scalar-pipe GEMM for attention scores.
// scores[b][t] = sum_k cw[k] * tanh(bias[k] + sum_h ht[h] * W[h][k]).
// Block 256 thr = 4 waves, 64 rows. ht staged in LDS (pad 129). Wave w owns
// k-group k0 = readfirstlane(w*32) -> W/bias/cw reads scalarize to s_load;
// lane l owns row l with acc[32] (~50 VGPR, under the ceiling).
// ---------------------------------------------------------------------------
__global__ __launch_bounds__(256, 4) void attn_scores_kernel(
    const float* __restrict__ word_weight, const float* __restrict__ word_bias,
    const float* __restrict__ context_weight, float* __restrict__ ws)
{
    const int tid = threadIdx.x;
    const int l   = tid & 63;       // row within block
    const int wv  = tid >> 6;       // wave = k-group
    const float* __restrict__ hs_f = ws + OFF_HS_F;
    const float* __restrict__ hs_b = ws + OFF_HS_B;
    float* __restrict__ sc = ws + OFF_SC;

    __shared__ float ht[64][129];   // 64 rows x 128 h, +1 pad
    __shared__ float part[4][64];

    const int r0 = blockIdx.x * 64;     // row r = t*512 + b; 64 rows, same t
    const int t  = r0 >> 9;
    const int b0 = r0 & 511;

    {
        const float* __restrict__ srcf = hs_f + (size_t)t * (B_SZ * H_DIM) + b0 * H_DIM;
        const float* __restrict__ srcb = hs_b + (size_t)t * (B_SZ * H_DIM) + b0 * H_DIM;
#pragma unroll
        for (int i = 0; i < 16; ++i) {
            const int idx = tid + i * 256;          // 0..4095
            const int row = idx >> 6, hh = idx & 63;
            ht[row][hh]      = srcf[idx];
            ht[row][64 + hh] = srcb[idx];
        }
    }
    __syncthreads();

    const int k0 = __builtin_amdgcn_readfirstlane(wv * 32);

    float acc[32];
#pragma unroll
    for (int k = 0; k < 32; ++k) acc[k] = word_bias[k0 + k];

#pragma unroll 4
    for (int h = 0; h < 128; ++h) {
        const float hv = ht[l][h];
        const float* __restrict__ wrow = word_weight + h * 128 + k0;
#pragma unroll
        for (int k = 0; k < 32; ++k) acc[k] = fmaf(hv, wrow[k], acc[k]);
    }

    float p = 0.f;
#pragma unroll
    for (int k = 0; k < 32; ++k) p += tanh_fast(acc[k]) * context_weight[k0 + k];
    part[wv][l] = p;
    __syncthreads();

    if (wv == 0) {
        sc[(b0 + l) * T_LEN + t] =
            (part[0][l] + part[1][l]) + (part[2][l] + part[3][l]);
    }
}

// ---------------------------------------------------------------------------
// Kernel D (fused): per batch row b — softmax over t of sc[b][:], then
// s_i[b][k] = sum_t a[t] * ht[t][b][k].  Block 512 threads = 8 waves.
// ---------------------------------------------------------------------------
__global__ __launch_bounds__(512, 2) void softmax_wsum_kernel(
    const float* __restrict__ ws_c, float* __restrict__ d_out)
{
    const float* __restrict__ hs_f = ws_c + OFF_HS_F;
    const float* __restrict__ hs_b = ws_c + OFF_HS_B;
    const float* __restrict__ sc   = ws_c + OFF_SC;
    const int b   = blockIdx.x;
    const int tid = threadIdx.x;

    __shared__ float red[8];
    __shared__ float sa[T_LEN];
    __shared__ float psum[4][TWOH];

    // ---- phase 1: softmax over t ----
    {
        const int t = tid;
        const int w = t >> 6;
        float v = sc[b * 512 + t];

        float m = v;
#pragma unroll
        for (int off = 32; off >= 1; off >>= 1) m = fmaxf(m, __shfl_xor(m, off));
        if ((t & 63) == 0) red[w] = m;
        __syncthreads();
        float mm = red[0];
#pragma unroll
        for (int i = 1; i < 8; ++i) mm = fmaxf(mm, red[i]);
        __syncthreads();

        const float e = __expf(v - mm);
        float ssum = e;
#pragma unroll
        for (int off = 32; off >= 1; off >>= 1) ssum += __shfl_xor(ssum, off);
        if ((t & 63) == 0) red[w] = ssum;
        __syncthreads();
        float tot = 0.f;
#pragma unroll
        for (int i = 0; i < 8; ++i) tot += red[i];

        sa[t] = e / tot;
    }
    __syncthreads();

    // ---- phase 2: weighted sum over t ----
    {
        const int k = tid & 127;
        const int c = tid >> 7;             // t-chunk 0..3
        const float* __restrict__ src =
            ((k < 64) ? hs_f : hs_b) + (k & 63) + b * H_DIM;
        const int t0 = c * 128;

        float acc = 0.f, acc2 = 0.f;
#pragma unroll 8
        for (int t = 0; t < 128; t += 2) {
            acc  = fmaf(sa[t0 + t],     src[(size_t)(t0 + t)     * (B_SZ * H_DIM)], acc);
            acc2 = fmaf(sa[t0 + t + 1], src[(size_t)(t0 + t + 1) * (B_SZ * H_DIM)], acc2);
        }
        psum[c][k] = acc + acc2;
    }
    __syncthreads();
    if (tid < TWOH) {
        d_out[b * TWOH + tid] =
            (psum[0][tid] + psum[1][tid]) + (psum[2][tid] + psum[3][tid]);
    }
}

// ---------------------------------------------------------------------------
extern "C" void kernel_launch(void* const* d_in, const int* in_sizes, int n_in,
                              void* d_out, int out_size, void* d_ws, size_t ws_size,
                              hipStream_t stream)
{
    const int*   input  = (const int*)  d_in[0];
    const float* hidden = (const float*)d_in[1];
    const float* embed  = (const float*)d_in[2];
    const float* word_w = (const float*)d_in[3];
    const float* word_b = (const float*)d_in[4];
    const float* ctx_w  = (const float*)d_in[5];
    const float* w_ih_f = (const float*)d_in[6];
    const float* w_hh_f = (const float*)d_in[7];
    const float* b_ih_f = (const float*)d_in[8];
    const float* b_hh_f = (const float*)d_in[9];
    const float* w_ih_b = (const float*)d_in[10];
    const float* w_hh_b = (const float*)d_in[11];
    const float* b_ih_b = (const float*)d_in[12];
    const float* b_hh_b = (const float*)d_in[13];
    float* ws  = (float*)d_ws;
    float* out = (float*)d_out;

    // A: vocab-folded input projection, both directions
    xgv_kernel<<<dim3((V_SZ + 63) / 64, 2), 256, 0, stream>>>(
        embed, w_ih_f, b_ih_f, w_ih_b, b_ih_b, ws);
    // B: sequential scan, 3 waves per (row, dir) -- gate-split
    gru_scan_kernel<<<dim3(B_SZ, 2), 192, 0, stream>>>(
        input, hidden, w_hh_f, b_hh_f, w_hh_b, b_hh_b, ws, out);
    // C: attention scores (scalar-pipe GEMM, 64 rows/block, 4 waves)
    attn_scores_kernel<<<(T_LEN * B_SZ) / 64, 256, 0, stream>>>(
        word_w, word_b, ctx_w, ws);
    // D: fused softmax over time + weighted sum -> s_i
    softmax_wsum_kernel<<<B_SZ, 512, 0, stream>>>(ws, out);
}